// Round 13
// baseline (1001.014 us; speedup 1.0000x reference)
//
#include <hip/hip_runtime.h>

#define BT 8192     // B*L
#define SEQL 512
#define DIM 768
#define HID 384
#define NG 1536     // 4*HID

using US = unsigned short;
typedef __bf16 bf16x8 __attribute__((ext_vector_type(8)));
typedef float f32x4 __attribute__((ext_vector_type(4)));

__device__ __forceinline__ float b2f(US u) {
  union { unsigned u; float f; } x; x.u = ((unsigned)u) << 16; return x.f;
}
__device__ __forceinline__ US f2b(float f) {
  __bf16 h = (__bf16)f;
  union { __bf16 h; US u; } x; x.h = h; return x.u;
}
__device__ __forceinline__ float fsig(float x) { return 1.f / (1.f + __expf(-x)); }
__device__ __forceinline__ float ftanh(float x) { return 1.f - 2.f / (__expf(2.f * x) + 1.f); }

// packed-fragment offset for a [128 rows][NCOL] tile set:
// [panel][kt][kk][wm][mi][lane][e]
__device__ __forceinline__ size_t pk_off(int panel, int rloc, int col, int panelStride) {
  return (size_t)panel * panelStride + (col >> 6) * 8192 + ((col >> 5) & 1) * 4096 +
         (rloc >> 6) * 2048 + ((rloc >> 4) & 3) * 512 +
         (((rloc & 15) | (((col & 31) >> 3) << 4))) * 8 + (col & 7);
}

// ---------------- weight pre-conversion ----------------
__global__ __launch_bounds__(256) void convW_ih_k(const float* __restrict__ WihF,
                                                  const float* __restrict__ WihB,
                                                  US* __restrict__ WihP) {
  int d = blockIdx.z;
  const float* src = d ? WihB : WihF;
  size_t idx = (size_t)blockIdx.x * 256 + threadIdx.x;  // 442368 frags per dir
  int lane = (int)(idx & 63);
  int t = (int)(idx >> 6);
  int sg = t & 3;
  int wn = (t >> 2) & 1;
  int kk = (t >> 3) & 1;
  int kt = (t >> 4) % 12;
  int nb = (t / 192) % 12;
  int wi = t / (192 * 12);
  int srow = sg * HID + nb * 32 + wn * 16 + (lane & 15);
  int scol = kt * 64 + kk * 32 + (lane >> 4) * 8;
  const float* s = src + ((size_t)wi * NG + srow) * DIM + scol;
  float4 v0 = *(const float4*)s;
  float4 v1 = *(const float4*)(s + 4);
  ushort4 o0, o1;
  o0.x = f2b(v0.x); o0.y = f2b(v0.y); o0.z = f2b(v0.z); o0.w = f2b(v0.w);
  o1.x = f2b(v1.x); o1.y = f2b(v1.y); o1.z = f2b(v1.z); o1.w = f2b(v1.w);
  US* dst = WihP + ((size_t)d * 442368 + idx) * 8;
  *(ushort4*)dst = o0;
  *(ushort4*)(dst + 4) = o1;
}

__global__ __launch_bounds__(256) void convW_hh_k(const float* __restrict__ WhhF,
                                                  const float* __restrict__ WhhB,
                                                  US* __restrict__ WhhP) {
  int d = blockIdx.z;
  const float* src = d ? WhhB : WhhF;
  size_t idx = (size_t)blockIdx.x * 256 + threadIdx.x;  // 221184 frags per dir
  int lane = (int)(idx & 63);
  int t = (int)(idx >> 6);
  int sg = t & 3;
  int wn = (t >> 2) & 1;
  int kk = (t >> 3) & 1;
  int kt = (t >> 4) % 6;
  int hb = (t / 96) % 12;
  int wi = t / (96 * 12);
  int srow = sg * HID + hb * 32 + wn * 16 + (lane & 15);
  int scol = kt * 64 + kk * 32 + (lane >> 4) * 8;
  const float* s = src + ((size_t)wi * NG + srow) * HID + scol;
  float4 v0 = *(const float4*)s;
  float4 v1 = *(const float4*)(s + 4);
  ushort4 o0, o1;
  o0.x = f2b(v0.x); o0.y = f2b(v0.y); o0.z = f2b(v0.z); o0.w = f2b(v0.w);
  o1.x = f2b(v1.x); o1.y = f2b(v1.y); o1.z = f2b(v1.z); o1.w = f2b(v1.w);
  US* dst = WhhP + ((size_t)d * 221184 + idx) * 8;
  *(ushort4*)dst = o0;
  *(ushort4*)(dst + 4) = o1;
}

// KAN coef: pack into [g][i][32] bf16: slots 0..10 = cos coefs, 16..26 = sin coefs
__global__ __launch_bounds__(256) void conv_coef_k(const float* __restrict__ coef,
                                                   US* __restrict__ coefP) {
  int idx = blockIdx.x * 256 + threadIdx.x;  // 3*768*32 = 73728
  int s = idx & 31;
  int i = (idx >> 5) % DIM;
  int g = idx / (32 * DIM);
  float v = 0.f;
  int o = s & 15;
  if (o < 11) v = coef[(size_t)((s >> 4) * 33 + o * 3 + g) * DIM + i];
  coefP[idx] = f2b(v);
}

// ---------------- compaction ----------------
__global__ void scan_k(const int* __restrict__ valid, int* __restrict__ dest) {
  __shared__ int s[SEQL];
  int b = blockIdx.x, l = threadIdx.x;
  int v = (valid[b * SEQL + l] == 1) ? 1 : 0;
  s[l] = v;
  __syncthreads();
  for (int off = 1; off < SEQL; off <<= 1) {
    int t = (l >= off) ? s[l - off] : 0;
    __syncthreads();
    s[l] += t;
    __syncthreads();
  }
  dest[b * SEQL + l] = v ? (s[l] - 1) : -1;
}

__global__ __launch_bounds__(256) void scatter_k(const float* __restrict__ seq,
                                                 const int* __restrict__ dest,
                                                 US* __restrict__ xcP) {
  int idx = blockIdx.x * 256 + threadIdx.x;  // BT*192 float4 chunks
  int p = idx / 192, cc = idx - p * 192;
  int d = dest[p];
  if (d < 0) return;
  int b = p >> 9;
  float4 v = ((const float4*)seq)[(size_t)p * 192 + cc];
  ushort4 o;
  o.x = f2b(v.x); o.y = f2b(v.y); o.z = f2b(v.z); o.w = f2b(v.w);
  int pdst = b * SEQL + d;
  int c = cc * 4;
  size_t off = pk_off(pdst >> 7, pdst & 127, c, 98304);
  *(ushort4*)&xcP[off] = o;
}

// ---------------- gate pre-GEMM (LDS-free) ----------------
__global__ __launch_bounds__(256, 4) void gate_gemm_k(
    const US* __restrict__ xcP, const US* __restrict__ WihP,
    const float* __restrict__ bihF, const float* __restrict__ bihB,
    const float* __restrict__ bhhF, const float* __restrict__ bhhB,
    US* __restrict__ G, int dirBase, size_t gStr) {
  int zi = blockIdx.z;
  int wi = zi % 3, drz = zi / 3, dr = dirBase + drz;
  const float* bih = dr ? bihB : bihF;
  const float* bhh = dr ? bhhB : bhhF;
  int panel = blockIdx.x, nb = blockIdx.y;
  const US* Wp = WihP + ((size_t)(dr * 3 + wi) * 12 + nb) * 98304;
  US* Gw = G + (size_t)drz * gStr + (size_t)wi * BT * NG;
  __shared__ float biasS[128];
  int tid = threadIdx.x, lane = tid & 63, wid = tid >> 6;
  int wm = wid >> 1, wn = wid & 1;
  if (tid < 128) {
    int sg = tid >> 5, hl = tid & 31;
    int gc = wi * NG + sg * HID + nb * 32 + hl;
    biasS[tid] = bih[gc] + bhh[gc];
  }
  __syncthreads();
  f32x4 acc[4][4] = {};
  const US* Ab = xcP + (size_t)panel * 98304 + (size_t)wm * 2048 + (size_t)lane * 8;
  const US* Bb = Wp + (size_t)wn * 2048 + (size_t)lane * 8;
#pragma unroll 2
  for (int kp = 0; kp < 24; ++kp) {
    bf16x8 a[4], b[4];
    const US* ap = Ab + (size_t)kp * 4096;
    const US* bp = Bb + (size_t)kp * 4096;
#pragma unroll
    for (int mi = 0; mi < 4; ++mi) a[mi] = *(const bf16x8*)(ap + (size_t)mi * 512);
#pragma unroll
    for (int sg = 0; sg < 4; ++sg) b[sg] = *(const bf16x8*)(bp + (size_t)sg * 512);
#pragma unroll
    for (int mi = 0; mi < 4; ++mi)
#pragma unroll
      for (int sg = 0; sg < 4; ++sg)
        acc[mi][sg] = __builtin_amdgcn_mfma_f32_16x16x32_bf16(a[mi], b[sg], acc[mi][sg], 0, 0, 0);
  }
  int hh = wn * 16 + (lane & 15);
  int hidx = nb * 32 + hh;
  int m0 = panel * 128;
#pragma unroll
  for (int mi = 0; mi < 4; ++mi) {
#pragma unroll
    for (int r = 0; r < 4; ++r) {
      int p = m0 + wm * 64 + mi * 16 + ((lane >> 4) << 2) + r;
      ushort4 gv;
      gv.x = f2b(acc[mi][0][r] + biasS[hh]);
      gv.y = f2b(acc[mi][1][r] + biasS[32 + hh]);
      gv.z = f2b(acc[mi][2][r] + biasS[64 + hh]);
      gv.w = f2b(acc[mi][3][r] + biasS[96 + hh]);
      *(ushort4*)&Gw[(size_t)p * NG + (size_t)hidx * 4] = gv;
    }
  }
}

// ---------------- LSTM step 0 ----------------
__global__ __launch_bounds__(384) void step0_k(const US* __restrict__ G, US* __restrict__ C,
                                               US* __restrict__ hn, int dirBase,
                                               size_t gStr, size_t cStr, size_t hStr) {
  int zi = blockIdx.z;
  int wi = zi % 3, drz = zi / 3, dr = dirBase + drz;
  int half = wi + 1;
  int dlt = dr ? half : -half;
  int p = blockIdx.x, hidx = threadIdx.x;
  int l = p & (SEQL - 1);
  const US* Gw = G + (size_t)drz * gStr + (size_t)wi * BT * NG;
  float c = 0.f, h = 0.f;
  int t = l + dlt;
  if ((unsigned)t < (unsigned)SEQL) {
    ushort4 gv = *(const ushort4*)&Gw[(size_t)(p + dlt) * NG + (size_t)hidx * 4];
    c = fsig(b2f(gv.x)) * ftanh(b2f(gv.z));
    h = fsig(b2f(gv.w)) * ftanh(c);
  }
  C[(size_t)drz * cStr + (size_t)wi * BT * HID + (size_t)p * HID + hidx] = f2b(c);
  hn[(size_t)drz * hStr + (size_t)wi * BT * HID + pk_off(p >> 7, p & 127, hidx, 49152)] = f2b(h);
}

// ---------------- LSTM step s>=1 (LDS-free, packed-h, burst epilogue loads) ----------------
__global__ __launch_bounds__(256, 4) void step_k(
    const US* __restrict__ WhhP,
    const US* __restrict__ G, US* __restrict__ C,
    const US* __restrict__ hcur, US* __restrict__ hnxt, US* __restrict__ Outs,
    int s, int wi0, int nact, int dirBase,
    size_t gStr, size_t cStr, size_t hStr) {
  int zi = blockIdx.z;
  int wi = wi0 + zi % nact, drz = zi / nact, dr = dirBase + drz;
  int w = 2 * wi + 3, half = wi + 1;
  int j = dr ? (w - 1 - s) : s;
  int dlt = j - half;
  bool fin = (s == w - 1);
  const US* Gw = G + (size_t)drz * gStr + (size_t)wi * BT * NG;
  US* Cw = C + (size_t)drz * cStr + (size_t)wi * BT * HID;
  const US* hc = hcur + (size_t)drz * hStr + (size_t)wi * BT * HID;
  US* hn = hnxt + (size_t)drz * hStr + (size_t)wi * BT * HID;
  US* Ow = Outs + (size_t)wi * BT * DIM + (dr ? HID : 0);
  int panel = blockIdx.x, hb = blockIdx.y;
  const US* Wp = WhhP + ((size_t)(dr * 3 + wi) * 12 + hb) * 49152;
  int tid = threadIdx.x, lane = tid & 63, wid = tid >> 6;
  int wm = wid >> 1, wn = wid & 1;
  f32x4 acc[4][4] = {};

  const US* Ab = hc + (size_t)panel * 49152 + (size_t)wm * 2048 + (size_t)lane * 8;
  const US* Bb = Wp + (size_t)wn * 2048 + (size_t)lane * 8;
#pragma unroll 2
  for (int kp = 0; kp < 12; ++kp) {
    bf16x8 a[4], b[4];
    const US* ap = Ab + (size_t)kp * 4096;
    const US* bp = Bb + (size_t)kp * 4096;
#pragma unroll
    for (int mi = 0; mi < 4; ++mi) a[mi] = *(const bf16x8*)(ap + (size_t)mi * 512);
#pragma unroll
    for (int sg = 0; sg < 4; ++sg) b[sg] = *(const bf16x8*)(bp + (size_t)sg * 512);
#pragma unroll
    for (int mi = 0; mi < 4; ++mi)
#pragma unroll
      for (int sg = 0; sg < 4; ++sg)
        acc[mi][sg] = __builtin_amdgcn_mfma_f32_16x16x32_bf16(a[mi], b[sg], acc[mi][sg], 0, 0, 0);
  }
  int l15 = lane & 15, l4 = lane >> 4;
  int hh = wn * 16 + l15;
  int hidx = hb * 32 + hh;
  int m0 = panel * 128;
  size_t wbase = (size_t)panel * 49152 + (size_t)hb * 4096 + (size_t)wm * 2048 +
                 (size_t)(wn * 2 + (l15 >> 3)) * 128 + (l15 & 7);

  // burst-issue all epilogue loads (one HBM round-trip instead of 16 serialized)
  ushort4 gv[4][4];
  US cv[4][4];
#pragma unroll
  for (int mi = 0; mi < 4; ++mi)
#pragma unroll
    for (int r = 0; r < 4; ++r) {
      int p = m0 + wm * 64 + mi * 16 + (l4 << 2) + r;
      int l = p & (SEQL - 1);
      int pc = ((unsigned)(l + dlt) < (unsigned)SEQL) ? (p + dlt) : p;  // clamped (masked lanes discard)
      gv[mi][r] = *(const ushort4*)&Gw[(size_t)pc * NG + (size_t)hidx * 4];
      cv[mi][r] = Cw[(size_t)p * HID + hidx];
    }

#pragma unroll
  for (int mi = 0; mi < 4; ++mi) {
#pragma unroll
    for (int r = 0; r < 4; ++r) {
      int p = m0 + wm * 64 + mi * 16 + (l4 << 2) + r;
      int l = p & (SEQL - 1);
      size_t po = wbase + (size_t)mi * 512 + (size_t)((l4 << 2) + r) * 8;
      float hval;
      if ((unsigned)(l + dlt) < (unsigned)SEQL) {
        float gi = acc[mi][0][r] + b2f(gv[mi][r].x);
        float gf = acc[mi][1][r] + b2f(gv[mi][r].y);
        float gg = acc[mi][2][r] + b2f(gv[mi][r].z);
        float go = acc[mi][3][r] + b2f(gv[mi][r].w);
        float c = fsig(gf) * b2f(cv[mi][r]) + fsig(gi) * ftanh(gg);
        Cw[(size_t)p * HID + hidx] = f2b(c);
        hval = fsig(go) * ftanh(c);
      } else {
        hval = b2f(hc[po]);  // rare boundary rows: inline load
      }
      if (fin) Ow[(size_t)p * DIM + hidx] = f2b(hval);
      else hn[po] = f2b(hval);
    }
  }
}

// ---------------- attention + KAN head (4 tokens / block, LDS transpose-reduce) ----------------
#define RSTR 260  // LDS row stride (floats): 16B-aligned rows, bank-shift 4/row
__global__ __launch_bounds__(256) void attn_kan_k(
    const US* __restrict__ Outs, const US* __restrict__ coefP,
    const float* __restrict__ kbias, float* __restrict__ out) {
  int p4 = blockIdx.x * 4;
  int tid = threadIdx.x, lane = tid & 63, wid = tid >> 6;
  __shared__ float lds[44 * RSTR];  // 45.8 KB; lds[0..175] doubles as softmax red
  float sq[3][4];
  {
    float o0[3][4], o1[3][4], o2[3][4], q[3][4];
#pragma unroll
    for (int c = 0; c < 3; ++c) {
      int i = tid + 256 * c;
#pragma unroll
      for (int t = 0; t < 4; ++t) {
        o0[c][t] = b2f(Outs[(size_t)(p4 + t) * DIM + i]);
        o1[c][t] = b2f(Outs[(size_t)(BT + p4 + t) * DIM + i]);
        o2[c][t] = b2f(Outs[(size_t)(2 * BT + p4 + t) * DIM + i]);
        q[c][t] = o0[c][t] + o1[c][t] + o2[c][t];
      }
    }
    float d[3][4];
#pragma unroll
    for (int t = 0; t < 4; ++t) {
      d[0][t] = 0.f; d[1][t] = 0.f; d[2][t] = 0.f;
#pragma unroll
      for (int c = 0; c < 3; ++c) {
        d[0][t] += q[c][t] * o0[c][t];
        d[1][t] += q[c][t] * o1[c][t];
        d[2][t] += q[c][t] * o2[c][t];
      }
    }
#pragma unroll
    for (int off = 32; off; off >>= 1)
#pragma unroll
      for (int t = 0; t < 4; ++t) {
        d[0][t] += __shfl_down(d[0][t], off);
        d[1][t] += __shfl_down(d[1][t], off);
        d[2][t] += __shfl_down(d[2][t], off);
      }
    if (lane == 0)
#pragma unroll
      for (int t = 0; t < 4; ++t) {
        lds[(t * 3 + 0) * 4 + wid] = d[0][t];
        lds[(t * 3 + 1) * 4 + wid] = d[1][t];
        lds[(t * 3 + 2) * 4 + wid] = d[2][t];
      }
    __syncthreads();
    const float scl = 0.03608439182435161f;  // 1/sqrt(768)
#pragma unroll
    for (int t = 0; t < 4; ++t) {
      float s0 = (lds[(t * 3) * 4] + lds[(t * 3) * 4 + 1] + lds[(t * 3) * 4 + 2] + lds[(t * 3) * 4 + 3]) * scl;
      float s1 = (lds[(t * 3 + 1) * 4] + lds[(t * 3 + 1) * 4 + 1] + lds[(t * 3 + 1) * 4 + 2] + lds[(t * 3 + 1) * 4 + 3]) * scl;
      float s2 = (lds[(t * 3 + 2) * 4] + lds[(t * 3 + 2) * 4 + 1] + lds[(t * 3 + 2) * 4 + 2] + lds[(t * 3 + 2) * 4 + 3]) * scl;
      float mx = fmaxf(s0, fmaxf(s1, s2));
      float a0 = __expf(s0 - mx), a1 = __expf(s1 - mx), a2 = __expf(s2 - mx);
      float inv = 1.f / (a0 + a1 + a2);
      a0 *= inv; a1 *= inv; a2 *= inv;
#pragma unroll
      for (int c = 0; c < 3; ++c)
        sq[c][t] = q[c][t] + a0 * o0[c][t] + a1 * o1[c][t] + a2 * o2[c][t];
    }
  }
  float acc[11][4];
#pragma unroll
  for (int o = 0; o < 11; ++o)
#pragma unroll
    for (int t = 0; t < 4; ++t) acc[o][t] = 0.f;
#pragma unroll
  for (int c = 0; c < 3; ++c) {
    int i = tid + 256 * c;
#pragma unroll
    for (int g = 0; g < 3; ++g) {
      float sn[4], cs[4];
#pragma unroll
      for (int t = 0; t < 4; ++t) __sincosf(sq[c][t] * (float)(g + 1), &sn[t], &cs[t]);
      const US* cp = coefP + ((size_t)g * DIM + i) * 32;
      bf16x8 k0 = *(const bf16x8*)(cp);
      bf16x8 k1 = *(const bf16x8*)(cp + 8);
      bf16x8 k2 = *(const bf16x8*)(cp + 16);
      bf16x8 k3 = *(const bf16x8*)(cp + 24);
#pragma unroll
      for (int o = 0; o < 8; ++o) {
        float cc = (float)k0[o], ss = (float)k2[o];
#pragma unroll
        for (int t = 0; t < 4; ++t) acc[o][t] += cs[t] * cc + sn[t] * ss;
      }
#pragma unroll
      for (int o = 8; o < 11; ++o) {
        float cc = (float)k1[o - 8], ss = (float)k3[o - 8];
#pragma unroll
        for (int t = 0; t < 4; ++t) acc[o][t] += cs[t] * cc + sn[t] * ss;
      }
    }
  }
  __syncthreads();  // all softmax-red reads complete before overwrite
#pragma unroll
  for (int o = 0; o < 11; ++o)
#pragma unroll
    for (int t = 0; t < 4; ++t)
      lds[(o * 4 + t) * RSTR + tid] = acc[o][t];
  __syncthreads();
  if (tid < 176) {
    int r = tid >> 2, qq = tid & 3;
    const float4* pv = (const float4*)&lds[r * RSTR + qq * 64];
    float4 s4 = pv[0];
#pragma unroll
    for (int k = 1; k < 16; ++k) {
      float4 v = pv[k];
      s4.x += v.x; s4.y += v.y; s4.z += v.z; s4.w += v.w;
    }
    float v = (s4.x + s4.y) + (s4.z + s4.w);
    v += __shfl_down(v, 1);
    v += __shfl_down(v, 2);
    if (qq == 0) {
      int o = r >> 2, t = r & 3;
      out[(size_t)(p4 + t) * 11 + o] = v + kbias[o];
    }
  }
}

extern "C" void kernel_launch(void* const* d_in, const int* in_sizes, int n_in,
                              void* d_out, int out_size, void* d_ws, size_t ws_size,
                              hipStream_t stream) {
  const float* seq = (const float*)d_in[0];
  const float* WihF = (const float*)d_in[1];
  const float* WhhF = (const float*)d_in[2];
  const float* bihF = (const float*)d_in[3];
  const float* bhhF = (const float*)d_in[4];
  const float* WihB = (const float*)d_in[5];
  const float* WhhB = (const float*)d_in[6];
  const float* bihB = (const float*)d_in[7];
  const float* bhhB = (const float*)d_in[8];
  const float* coef = (const float*)d_in[9];
  const float* kbias = (const float*)d_in[10];
  const int* valid = (const int*)d_in[11];

  constexpr size_t SZ_XC = (size_t)BT * DIM * 2;             // 12.58 MB
  constexpr size_t SZ_DEST = (size_t)BT * 4;
  constexpr size_t SZ_CP = (size_t)3 * DIM * 32 * 2;
  constexpr size_t SZ_G1 = (size_t)3 * BT * NG * 2;          // 75.5 MB per dir
  constexpr size_t SZ_C1 = (size_t)3 * BT * HID * 2;
  constexpr size_t SZ_H1 = (size_t)3 * BT * HID * 2;
  constexpr size_t SZ_OUTS = (size_t)3 * BT * DIM * 2;
  constexpr size_t SZ_WIHP = (size_t)2 * 3 * NG * DIM * 2;
  constexpr size_t SZ_WHHP = (size_t)2 * 3 * NG * HID * 2;
  constexpr size_t GE = (size_t)3 * BT * NG;
  constexpr size_t CE = (size_t)3 * BT * HID;
  constexpr size_t HE = (size_t)3 * BT * HID;

  constexpr size_t NEED1 = SZ_XC + SZ_DEST + SZ_CP + SZ_WIHP + SZ_WHHP +
                           SZ_G1 + SZ_C1 + 2 * SZ_H1 + SZ_OUTS;          // ~204 MB
  constexpr size_t UNION = (SZ_XC + SZ_WIHP > SZ_OUTS) ? (SZ_XC + SZ_WIHP) : SZ_OUTS;
  constexpr size_t NEED2 = UNION + SZ_DEST + SZ_CP + SZ_WHHP +
                           2 * SZ_G1 + 2 * SZ_C1 + 4 * SZ_H1;            // ~309 MB
  if (ws_size < NEED1) return;
  const int ndir = (ws_size >= NEED2) ? 2 : 1;

  char* ws = (char*)d_ws;
  US *xcP, *coefP, *WihP, *WhhP, *G, *C, *h0, *h1, *Outs;
  int* dest;
  if (ndir == 2) {
    xcP = (US*)ws;
    WihP = (US*)(ws + SZ_XC);
    Outs = (US*)ws;                    // aliases xcP+WihP (dead after gate)
    char* p = ws + UNION;
    dest = (int*)p;                    p += SZ_DEST;
    coefP = (US*)p;                    p += SZ_CP;
    WhhP = (US*)p;                     p += SZ_WHHP;
    G = (US*)p;                        p += 2 * SZ_G1;
    C = (US*)p;                        p += 2 * SZ_C1;
    h0 = (US*)p;                       p += 2 * SZ_H1;
    h1 = (US*)p;
  } else {
    char* p = ws;
    xcP = (US*)p;                      p += SZ_XC;
    dest = (int*)p;                    p += SZ_DEST;
    coefP = (US*)p;                    p += SZ_CP;
    WihP = (US*)p;                     p += SZ_WIHP;
    WhhP = (US*)p;                     p += SZ_WHHP;
    G = (US*)p;                        p += SZ_G1;
    C = (US*)p;                        p += SZ_C1;
    h0 = (US*)p;                       p += SZ_H1;
    h1 = (US*)p;                       p += SZ_H1;
    Outs = (US*)p;
  }
  float* out = (float*)d_out;

  hipMemsetAsync(xcP, 0, SZ_XC, stream);
  scan_k<<<16, SEQL, 0, stream>>>(valid, dest);
  scatter_k<<<(BT * 192) / 256, 256, 0, stream>>>(seq, dest, xcP);
  conv_coef_k<<<288, 256, 0, stream>>>(coef, coefP);
  convW_ih_k<<<dim3(442368 / 256, 1, 2), 256, 0, stream>>>(WihF, WihB, WihP);
  convW_hh_k<<<dim3(221184 / 256, 1, 2), 256, 0, stream>>>(WhhF, WhhB, WhhP);

  if (ndir == 2) {
    gate_gemm_k<<<dim3(64, 12, 6), 256, 0, stream>>>(xcP, WihP, bihF, bihB, bhhF, bhhB,
                                                     G, 0, GE);
    step0_k<<<dim3(BT, 1, 6), HID, 0, stream>>>(G, C, h1, 0, GE, CE, HE);
    for (int s = 1; s < 7; ++s) {
      int nact = (s < 3) ? 3 : ((s < 5) ? 2 : 1);
      int wi0 = 3 - nact;
      US* hcur = (s & 1) ? h1 : h0;
      US* hnxt = (s & 1) ? h0 : h1;
      step_k<<<dim3(64, 12, nact * 2), 256, 0, stream>>>(WhhP, G, C, hcur, hnxt, Outs,
                                                         s, wi0, nact, 0, GE, CE, HE);
    }
  } else {
    for (int dir = 0; dir < 2; ++dir) {
      gate_gemm_k<<<dim3(64, 12, 3), 256, 0, stream>>>(xcP, WihP, bihF, bihB, bhhF, bhhB,
                                                       G, dir, 0);
      step0_k<<<dim3(BT, 1, 3), HID, 0, stream>>>(G, C, h1, dir, 0, 0, 0);
      for (int s = 1; s < 7; ++s) {
        int nact = (s < 3) ? 3 : ((s < 5) ? 2 : 1);
        int wi0 = 3 - nact;
        US* hcur = (s & 1) ? h1 : h0;
        US* hnxt = (s & 1) ? h0 : h1;
        step_k<<<dim3(64, 12, nact), 256, 0, stream>>>(WhhP, G, C, hcur, hnxt, Outs,
                                                       s, wi0, nact, dir, 0, 0, 0);
      }
    }
  }
  attn_kan_k<<<BT / 4, 256, 0, stream>>>(Outs, coefP, kbias, out);
}

// Round 14
// 716.872 us; speedup vs baseline: 1.3964x; 1.3964x over previous
//
#include <hip/hip_runtime.h>

#define BT 8192     // B*L
#define SEQL 512
#define DIM 768
#define HID 384
#define NG 1536     // 4*HID

using US = unsigned short;
typedef __bf16 bf16x8 __attribute__((ext_vector_type(8)));
typedef float f32x4 __attribute__((ext_vector_type(4)));

__device__ __forceinline__ float b2f(US u) {
  union { unsigned u; float f; } x; x.u = ((unsigned)u) << 16; return x.f;
}
__device__ __forceinline__ US f2b(float f) {
  __bf16 h = (__bf16)f;
  union { __bf16 h; US u; } x; x.h = h; return x.u;
}
__device__ __forceinline__ float fsig(float x) { return 1.f / (1.f + __expf(-x)); }
__device__ __forceinline__ float ftanh(float x) { return 1.f - 2.f / (__expf(2.f * x) + 1.f); }

// packed-fragment offset for a [128 rows][NCOL] tile set:
// [panel][kt][kk][wm][mi][lane][e]
__device__ __forceinline__ size_t pk_off(int panel, int rloc, int col, int panelStride) {
  return (size_t)panel * panelStride + (col >> 6) * 8192 + ((col >> 5) & 1) * 4096 +
         (rloc >> 6) * 2048 + ((rloc >> 4) & 3) * 512 +
         (((rloc & 15) | (((col & 31) >> 3) << 4))) * 8 + (col & 7);
}

// ---------------- weight pre-conversion ----------------
__global__ __launch_bounds__(256) void convW_ih_k(const float* __restrict__ WihF,
                                                  const float* __restrict__ WihB,
                                                  US* __restrict__ WihP) {
  int d = blockIdx.z;
  const float* src = d ? WihB : WihF;
  size_t idx = (size_t)blockIdx.x * 256 + threadIdx.x;  // 442368 frags per dir
  int lane = (int)(idx & 63);
  int t = (int)(idx >> 6);
  int sg = t & 3;
  int wn = (t >> 2) & 1;
  int kk = (t >> 3) & 1;
  int kt = (t >> 4) % 12;
  int nb = (t / 192) % 12;
  int wi = t / (192 * 12);
  int srow = sg * HID + nb * 32 + wn * 16 + (lane & 15);
  int scol = kt * 64 + kk * 32 + (lane >> 4) * 8;
  const float* s = src + ((size_t)wi * NG + srow) * DIM + scol;
  float4 v0 = *(const float4*)s;
  float4 v1 = *(const float4*)(s + 4);
  ushort4 o0, o1;
  o0.x = f2b(v0.x); o0.y = f2b(v0.y); o0.z = f2b(v0.z); o0.w = f2b(v0.w);
  o1.x = f2b(v1.x); o1.y = f2b(v1.y); o1.z = f2b(v1.z); o1.w = f2b(v1.w);
  US* dst = WihP + ((size_t)d * 442368 + idx) * 8;
  *(ushort4*)dst = o0;
  *(ushort4*)(dst + 4) = o1;
}

__global__ __launch_bounds__(256) void convW_hh_k(const float* __restrict__ WhhF,
                                                  const float* __restrict__ WhhB,
                                                  US* __restrict__ WhhP) {
  int d = blockIdx.z;
  const float* src = d ? WhhB : WhhF;
  size_t idx = (size_t)blockIdx.x * 256 + threadIdx.x;  // 221184 frags per dir
  int lane = (int)(idx & 63);
  int t = (int)(idx >> 6);
  int sg = t & 3;
  int wn = (t >> 2) & 1;
  int kk = (t >> 3) & 1;
  int kt = (t >> 4) % 6;
  int hb = (t / 96) % 12;
  int wi = t / (96 * 12);
  int srow = sg * HID + hb * 32 + wn * 16 + (lane & 15);
  int scol = kt * 64 + kk * 32 + (lane >> 4) * 8;
  const float* s = src + ((size_t)wi * NG + srow) * HID + scol;
  float4 v0 = *(const float4*)s;
  float4 v1 = *(const float4*)(s + 4);
  ushort4 o0, o1;
  o0.x = f2b(v0.x); o0.y = f2b(v0.y); o0.z = f2b(v0.z); o0.w = f2b(v0.w);
  o1.x = f2b(v1.x); o1.y = f2b(v1.y); o1.z = f2b(v1.z); o1.w = f2b(v1.w);
  US* dst = WhhP + ((size_t)d * 221184 + idx) * 8;
  *(ushort4*)dst = o0;
  *(ushort4*)(dst + 4) = o1;
}

// KAN coef: pack into [g][i][32] bf16: slots 0..10 = cos coefs, 16..26 = sin coefs
__global__ __launch_bounds__(256) void conv_coef_k(const float* __restrict__ coef,
                                                   US* __restrict__ coefP) {
  int idx = blockIdx.x * 256 + threadIdx.x;  // 3*768*32 = 73728
  int s = idx & 31;
  int i = (idx >> 5) % DIM;
  int g = idx / (32 * DIM);
  float v = 0.f;
  int o = s & 15;
  if (o < 11) v = coef[(size_t)((s >> 4) * 33 + o * 3 + g) * DIM + i];
  coefP[idx] = f2b(v);
}

// ---------------- compaction ----------------
__global__ void scan_k(const int* __restrict__ valid, int* __restrict__ dest) {
  __shared__ int s[SEQL];
  int b = blockIdx.x, l = threadIdx.x;
  int v = (valid[b * SEQL + l] == 1) ? 1 : 0;
  s[l] = v;
  __syncthreads();
  for (int off = 1; off < SEQL; off <<= 1) {
    int t = (l >= off) ? s[l - off] : 0;
    __syncthreads();
    s[l] += t;
    __syncthreads();
  }
  dest[b * SEQL + l] = v ? (s[l] - 1) : -1;
}

__global__ __launch_bounds__(256) void scatter_k(const float* __restrict__ seq,
                                                 const int* __restrict__ dest,
                                                 US* __restrict__ xcP) {
  int idx = blockIdx.x * 256 + threadIdx.x;  // BT*192 float4 chunks
  int p = idx / 192, cc = idx - p * 192;
  int d = dest[p];
  if (d < 0) return;
  int b = p >> 9;
  float4 v = ((const float4*)seq)[(size_t)p * 192 + cc];
  ushort4 o;
  o.x = f2b(v.x); o.y = f2b(v.y); o.z = f2b(v.z); o.w = f2b(v.w);
  int pdst = b * SEQL + d;
  int c = cc * 4;
  size_t off = pk_off(pdst >> 7, pdst & 127, c, 98304);
  *(ushort4*)&xcP[off] = o;
}

// ---------------- gate pre-GEMM (LDS-free) ----------------
__global__ __launch_bounds__(256, 4) void gate_gemm_k(
    const US* __restrict__ xcP, const US* __restrict__ WihP,
    const float* __restrict__ bihF, const float* __restrict__ bihB,
    const float* __restrict__ bhhF, const float* __restrict__ bhhB,
    US* __restrict__ G, int dirBase, size_t gStr) {
  int zi = blockIdx.z;
  int wi = zi % 3, drz = zi / 3, dr = dirBase + drz;
  const float* bih = dr ? bihB : bihF;
  const float* bhh = dr ? bhhB : bhhF;
  int panel = blockIdx.x, nb = blockIdx.y;
  const US* Wp = WihP + ((size_t)(dr * 3 + wi) * 12 + nb) * 98304;
  US* Gw = G + (size_t)drz * gStr + (size_t)wi * BT * NG;
  __shared__ float biasS[128];
  int tid = threadIdx.x, lane = tid & 63, wid = tid >> 6;
  int wm = wid >> 1, wn = wid & 1;
  if (tid < 128) {
    int sg = tid >> 5, hl = tid & 31;
    int gc = wi * NG + sg * HID + nb * 32 + hl;
    biasS[tid] = bih[gc] + bhh[gc];
  }
  __syncthreads();
  f32x4 acc[4][4] = {};
  const US* Ab = xcP + (size_t)panel * 98304 + (size_t)wm * 2048 + (size_t)lane * 8;
  const US* Bb = Wp + (size_t)wn * 2048 + (size_t)lane * 8;
#pragma unroll 2
  for (int kp = 0; kp < 24; ++kp) {
    bf16x8 a[4], b[4];
    const US* ap = Ab + (size_t)kp * 4096;
    const US* bp = Bb + (size_t)kp * 4096;
#pragma unroll
    for (int mi = 0; mi < 4; ++mi) a[mi] = *(const bf16x8*)(ap + (size_t)mi * 512);
#pragma unroll
    for (int sg = 0; sg < 4; ++sg) b[sg] = *(const bf16x8*)(bp + (size_t)sg * 512);
#pragma unroll
    for (int mi = 0; mi < 4; ++mi)
#pragma unroll
      for (int sg = 0; sg < 4; ++sg)
        acc[mi][sg] = __builtin_amdgcn_mfma_f32_16x16x32_bf16(a[mi], b[sg], acc[mi][sg], 0, 0, 0);
  }
  int hh = wn * 16 + (lane & 15);
  int hidx = nb * 32 + hh;
  int m0 = panel * 128;
#pragma unroll
  for (int mi = 0; mi < 4; ++mi) {
#pragma unroll
    for (int r = 0; r < 4; ++r) {
      int p = m0 + wm * 64 + mi * 16 + ((lane >> 4) << 2) + r;
      ushort4 gv;
      gv.x = f2b(acc[mi][0][r] + biasS[hh]);
      gv.y = f2b(acc[mi][1][r] + biasS[32 + hh]);
      gv.z = f2b(acc[mi][2][r] + biasS[64 + hh]);
      gv.w = f2b(acc[mi][3][r] + biasS[96 + hh]);
      *(ushort4*)&Gw[(size_t)p * NG + (size_t)hidx * 4] = gv;
    }
  }
}

// ---------------- LSTM step 0 ----------------
__global__ __launch_bounds__(384) void step0_k(const US* __restrict__ G, US* __restrict__ C,
                                               US* __restrict__ hn, int dirBase,
                                               size_t gStr, size_t cStr, size_t hStr) {
  int zi = blockIdx.z;
  int wi = zi % 3, drz = zi / 3, dr = dirBase + drz;
  int half = wi + 1;
  int dlt = dr ? half : -half;
  int p = blockIdx.x, hidx = threadIdx.x;
  int l = p & (SEQL - 1);
  const US* Gw = G + (size_t)drz * gStr + (size_t)wi * BT * NG;
  float c = 0.f, h = 0.f;
  int t = l + dlt;
  if ((unsigned)t < (unsigned)SEQL) {
    ushort4 gv = *(const ushort4*)&Gw[(size_t)(p + dlt) * NG + (size_t)hidx * 4];
    c = fsig(b2f(gv.x)) * ftanh(b2f(gv.z));
    h = fsig(b2f(gv.w)) * ftanh(c);
  }
  C[(size_t)drz * cStr + (size_t)wi * BT * HID + (size_t)p * HID + hidx] = f2b(c);
  hn[(size_t)drz * hStr + (size_t)wi * BT * HID + pk_off(p >> 7, p & 127, hidx, 49152)] = f2b(h);
}

// ---------------- LSTM step s>=1 (LDS-free, packed-h, per-mi burst epilogue) ----------------
__global__ __launch_bounds__(256, 4) void step_k(
    const US* __restrict__ WhhP,
    const US* __restrict__ G, US* __restrict__ C,
    const US* __restrict__ hcur, US* __restrict__ hnxt, US* __restrict__ Outs,
    int s, int wi0, int nact, int dirBase,
    size_t gStr, size_t cStr, size_t hStr) {
  int zi = blockIdx.z;
  int wi = wi0 + zi % nact, drz = zi / nact, dr = dirBase + drz;
  int w = 2 * wi + 3, half = wi + 1;
  int j = dr ? (w - 1 - s) : s;
  int dlt = j - half;
  bool fin = (s == w - 1);
  const US* Gw = G + (size_t)drz * gStr + (size_t)wi * BT * NG;
  US* Cw = C + (size_t)drz * cStr + (size_t)wi * BT * HID;
  const US* hc = hcur + (size_t)drz * hStr + (size_t)wi * BT * HID;
  US* hn = hnxt + (size_t)drz * hStr + (size_t)wi * BT * HID;
  US* Ow = Outs + (size_t)wi * BT * DIM + (dr ? HID : 0);
  int panel = blockIdx.x, hb = blockIdx.y;
  const US* Wp = WhhP + ((size_t)(dr * 3 + wi) * 12 + hb) * 49152;
  int tid = threadIdx.x, lane = tid & 63, wid = tid >> 6;
  int wm = wid >> 1, wn = wid & 1;
  f32x4 acc[4][4] = {};

  const US* Ab = hc + (size_t)panel * 49152 + (size_t)wm * 2048 + (size_t)lane * 8;
  const US* Bb = Wp + (size_t)wn * 2048 + (size_t)lane * 8;
#pragma unroll 2
  for (int kp = 0; kp < 12; ++kp) {
    bf16x8 a[4], b[4];
    const US* ap = Ab + (size_t)kp * 4096;
    const US* bp = Bb + (size_t)kp * 4096;
#pragma unroll
    for (int mi = 0; mi < 4; ++mi) a[mi] = *(const bf16x8*)(ap + (size_t)mi * 512);
#pragma unroll
    for (int sg = 0; sg < 4; ++sg) b[sg] = *(const bf16x8*)(bp + (size_t)sg * 512);
#pragma unroll
    for (int mi = 0; mi < 4; ++mi)
#pragma unroll
      for (int sg = 0; sg < 4; ++sg)
        acc[mi][sg] = __builtin_amdgcn_mfma_f32_16x16x32_bf16(a[mi], b[sg], acc[mi][sg], 0, 0, 0);
  }
  int l15 = lane & 15, l4 = lane >> 4;
  int hh = wn * 16 + l15;
  int hidx = hb * 32 + hh;
  int m0 = panel * 128;
  size_t wbase = (size_t)panel * 49152 + (size_t)hb * 4096 + (size_t)wm * 2048 +
                 (size_t)(wn * 2 + (l15 >> 3)) * 128 + (l15 & 7);

  // per-mi mini-burst: 4 G + 4 C loads in flight (stays in the 64-VGPR budget, no spill)
#pragma unroll
  for (int mi = 0; mi < 4; ++mi) {
    ushort4 gv0, gv1, gv2, gv3;
    US cv0, cv1, cv2, cv3;
    {
      int pb = m0 + wm * 64 + mi * 16 + (l4 << 2);
      int l0 = pb & (SEQL - 1);
      // rows pb..pb+3 share validity windows individually; clamp per row
      int q0 = ((unsigned)((pb     & (SEQL - 1)) + dlt) < (unsigned)SEQL) ? pb + dlt : pb;
      int q1 = ((unsigned)(((pb+1) & (SEQL - 1)) + dlt) < (unsigned)SEQL) ? pb + 1 + dlt : pb + 1;
      int q2 = ((unsigned)(((pb+2) & (SEQL - 1)) + dlt) < (unsigned)SEQL) ? pb + 2 + dlt : pb + 2;
      int q3 = ((unsigned)(((pb+3) & (SEQL - 1)) + dlt) < (unsigned)SEQL) ? pb + 3 + dlt : pb + 3;
      (void)l0;
      gv0 = *(const ushort4*)&Gw[(size_t)q0 * NG + (size_t)hidx * 4];
      gv1 = *(const ushort4*)&Gw[(size_t)q1 * NG + (size_t)hidx * 4];
      gv2 = *(const ushort4*)&Gw[(size_t)q2 * NG + (size_t)hidx * 4];
      gv3 = *(const ushort4*)&Gw[(size_t)q3 * NG + (size_t)hidx * 4];
      cv0 = Cw[(size_t)(pb    ) * HID + hidx];
      cv1 = Cw[(size_t)(pb + 1) * HID + hidx];
      cv2 = Cw[(size_t)(pb + 2) * HID + hidx];
      cv3 = Cw[(size_t)(pb + 3) * HID + hidx];
    }
#pragma unroll
    for (int r = 0; r < 4; ++r) {
      ushort4 gvr = (r == 0) ? gv0 : (r == 1) ? gv1 : (r == 2) ? gv2 : gv3;
      US cvr = (r == 0) ? cv0 : (r == 1) ? cv1 : (r == 2) ? cv2 : cv3;
      int p = m0 + wm * 64 + mi * 16 + (l4 << 2) + r;
      int l = p & (SEQL - 1);
      size_t po = wbase + (size_t)mi * 512 + (size_t)((l4 << 2) + r) * 8;
      float hval;
      if ((unsigned)(l + dlt) < (unsigned)SEQL) {
        float gi = acc[mi][0][r] + b2f(gvr.x);
        float gf = acc[mi][1][r] + b2f(gvr.y);
        float gg = acc[mi][2][r] + b2f(gvr.z);
        float go = acc[mi][3][r] + b2f(gvr.w);
        float c = fsig(gf) * b2f(cvr) + fsig(gi) * ftanh(gg);
        Cw[(size_t)p * HID + hidx] = f2b(c);
        hval = fsig(go) * ftanh(c);
      } else {
        hval = b2f(hc[po]);  // rare boundary rows: inline load
      }
      if (fin) Ow[(size_t)p * DIM + hidx] = f2b(hval);
      else hn[po] = f2b(hval);
    }
  }
}

// ---------------- attention + KAN head (4 tokens / block, LDS transpose-reduce) ----------------
#define RSTR 260  // LDS row stride (floats): 16B-aligned rows, bank-shift 4/row
__global__ __launch_bounds__(256) void attn_kan_k(
    const US* __restrict__ Outs, const US* __restrict__ coefP,
    const float* __restrict__ kbias, float* __restrict__ out) {
  int p4 = blockIdx.x * 4;
  int tid = threadIdx.x, lane = tid & 63, wid = tid >> 6;
  __shared__ float lds[44 * RSTR];  // 45.8 KB; lds[0..175] doubles as softmax red
  float sq[3][4];
  {
    float o0[3][4], o1[3][4], o2[3][4], q[3][4];
#pragma unroll
    for (int c = 0; c < 3; ++c) {
      int i = tid + 256 * c;
#pragma unroll
      for (int t = 0; t < 4; ++t) {
        o0[c][t] = b2f(Outs[(size_t)(p4 + t) * DIM + i]);
        o1[c][t] = b2f(Outs[(size_t)(BT + p4 + t) * DIM + i]);
        o2[c][t] = b2f(Outs[(size_t)(2 * BT + p4 + t) * DIM + i]);
        q[c][t] = o0[c][t] + o1[c][t] + o2[c][t];
      }
    }
    float d[3][4];
#pragma unroll
    for (int t = 0; t < 4; ++t) {
      d[0][t] = 0.f; d[1][t] = 0.f; d[2][t] = 0.f;
#pragma unroll
      for (int c = 0; c < 3; ++c) {
        d[0][t] += q[c][t] * o0[c][t];
        d[1][t] += q[c][t] * o1[c][t];
        d[2][t] += q[c][t] * o2[c][t];
      }
    }
#pragma unroll
    for (int off = 32; off; off >>= 1)
#pragma unroll
      for (int t = 0; t < 4; ++t) {
        d[0][t] += __shfl_down(d[0][t], off);
        d[1][t] += __shfl_down(d[1][t], off);
        d[2][t] += __shfl_down(d[2][t], off);
      }
    if (lane == 0)
#pragma unroll
      for (int t = 0; t < 4; ++t) {
        lds[(t * 3 + 0) * 4 + wid] = d[0][t];
        lds[(t * 3 + 1) * 4 + wid] = d[1][t];
        lds[(t * 3 + 2) * 4 + wid] = d[2][t];
      }
    __syncthreads();
    const float scl = 0.03608439182435161f;  // 1/sqrt(768)
#pragma unroll
    for (int t = 0; t < 4; ++t) {
      float s0 = (lds[(t * 3) * 4] + lds[(t * 3) * 4 + 1] + lds[(t * 3) * 4 + 2] + lds[(t * 3) * 4 + 3]) * scl;
      float s1 = (lds[(t * 3 + 1) * 4] + lds[(t * 3 + 1) * 4 + 1] + lds[(t * 3 + 1) * 4 + 2] + lds[(t * 3 + 1) * 4 + 3]) * scl;
      float s2 = (lds[(t * 3 + 2) * 4] + lds[(t * 3 + 2) * 4 + 1] + lds[(t * 3 + 2) * 4 + 2] + lds[(t * 3 + 2) * 4 + 3]) * scl;
      float mx = fmaxf(s0, fmaxf(s1, s2));
      float a0 = __expf(s0 - mx), a1 = __expf(s1 - mx), a2 = __expf(s2 - mx);
      float inv = 1.f / (a0 + a1 + a2);
      a0 *= inv; a1 *= inv; a2 *= inv;
#pragma unroll
      for (int c = 0; c < 3; ++c)
        sq[c][t] = q[c][t] + a0 * o0[c][t] + a1 * o1[c][t] + a2 * o2[c][t];
    }
  }
  float acc[11][4];
#pragma unroll
  for (int o = 0; o < 11; ++o)
#pragma unroll
    for (int t = 0; t < 4; ++t) acc[o][t] = 0.f;
#pragma unroll
  for (int c = 0; c < 3; ++c) {
    int i = tid + 256 * c;
#pragma unroll
    for (int g = 0; g < 3; ++g) {
      float sn[4], cs[4];
#pragma unroll
      for (int t = 0; t < 4; ++t) __sincosf(sq[c][t] * (float)(g + 1), &sn[t], &cs[t]);
      const US* cp = coefP + ((size_t)g * DIM + i) * 32;
      bf16x8 k0 = *(const bf16x8*)(cp);
      bf16x8 k1 = *(const bf16x8*)(cp + 8);
      bf16x8 k2 = *(const bf16x8*)(cp + 16);
      bf16x8 k3 = *(const bf16x8*)(cp + 24);
#pragma unroll
      for (int o = 0; o < 8; ++o) {
        float cc = (float)k0[o], ss = (float)k2[o];
#pragma unroll
        for (int t = 0; t < 4; ++t) acc[o][t] += cs[t] * cc + sn[t] * ss;
      }
#pragma unroll
      for (int o = 8; o < 11; ++o) {
        float cc = (float)k1[o - 8], ss = (float)k3[o - 8];
#pragma unroll
        for (int t = 0; t < 4; ++t) acc[o][t] += cs[t] * cc + sn[t] * ss;
      }
    }
  }
  __syncthreads();  // all softmax-red reads complete before overwrite
#pragma unroll
  for (int o = 0; o < 11; ++o)
#pragma unroll
    for (int t = 0; t < 4; ++t)
      lds[(o * 4 + t) * RSTR + tid] = acc[o][t];
  __syncthreads();
  if (tid < 176) {
    int r = tid >> 2, qq = tid & 3;
    const float4* pv = (const float4*)&lds[r * RSTR + qq * 64];
    float4 s4 = pv[0];
#pragma unroll
    for (int k = 1; k < 16; ++k) {
      float4 v = pv[k];
      s4.x += v.x; s4.y += v.y; s4.z += v.z; s4.w += v.w;
    }
    float v = (s4.x + s4.y) + (s4.z + s4.w);
    v += __shfl_down(v, 1);
    v += __shfl_down(v, 2);
    if (qq == 0) {
      int o = r >> 2, t = r & 3;
      out[(size_t)(p4 + t) * 11 + o] = v + kbias[o];
    }
  }
}

extern "C" void kernel_launch(void* const* d_in, const int* in_sizes, int n_in,
                              void* d_out, int out_size, void* d_ws, size_t ws_size,
                              hipStream_t stream) {
  const float* seq = (const float*)d_in[0];
  const float* WihF = (const float*)d_in[1];
  const float* WhhF = (const float*)d_in[2];
  const float* bihF = (const float*)d_in[3];
  const float* bhhF = (const float*)d_in[4];
  const float* WihB = (const float*)d_in[5];
  const float* WhhB = (const float*)d_in[6];
  const float* bihB = (const float*)d_in[7];
  const float* bhhB = (const float*)d_in[8];
  const float* coef = (const float*)d_in[9];
  const float* kbias = (const float*)d_in[10];
  const int* valid = (const int*)d_in[11];

  constexpr size_t SZ_XC = (size_t)BT * DIM * 2;             // 12.58 MB
  constexpr size_t SZ_DEST = (size_t)BT * 4;
  constexpr size_t SZ_CP = (size_t)3 * DIM * 32 * 2;
  constexpr size_t SZ_G1 = (size_t)3 * BT * NG * 2;          // 75.5 MB per dir
  constexpr size_t SZ_C1 = (size_t)3 * BT * HID * 2;
  constexpr size_t SZ_H1 = (size_t)3 * BT * HID * 2;
  constexpr size_t SZ_OUTS = (size_t)3 * BT * DIM * 2;
  constexpr size_t SZ_WIHP = (size_t)2 * 3 * NG * DIM * 2;
  constexpr size_t SZ_WHHP = (size_t)2 * 3 * NG * HID * 2;
  constexpr size_t GE = (size_t)3 * BT * NG;
  constexpr size_t CE = (size_t)3 * BT * HID;
  constexpr size_t HE = (size_t)3 * BT * HID;

  constexpr size_t NEED1 = SZ_XC + SZ_DEST + SZ_CP + SZ_WIHP + SZ_WHHP +
                           SZ_G1 + SZ_C1 + 2 * SZ_H1 + SZ_OUTS;          // ~204 MB
  constexpr size_t UNION = (SZ_XC + SZ_WIHP > SZ_OUTS) ? (SZ_XC + SZ_WIHP) : SZ_OUTS;
  constexpr size_t NEED2 = UNION + SZ_DEST + SZ_CP + SZ_WHHP +
                           2 * SZ_G1 + 2 * SZ_C1 + 4 * SZ_H1;            // ~309 MB
  if (ws_size < NEED1) return;
  const int ndir = (ws_size >= NEED2) ? 2 : 1;

  char* ws = (char*)d_ws;
  US *xcP, *coefP, *WihP, *WhhP, *G, *C, *h0, *h1, *Outs;
  int* dest;
  if (ndir == 2) {
    xcP = (US*)ws;
    WihP = (US*)(ws + SZ_XC);
    Outs = (US*)ws;                    // aliases xcP+WihP (dead after gate)
    char* p = ws + UNION;
    dest = (int*)p;                    p += SZ_DEST;
    coefP = (US*)p;                    p += SZ_CP;
    WhhP = (US*)p;                     p += SZ_WHHP;
    G = (US*)p;                        p += 2 * SZ_G1;
    C = (US*)p;                        p += 2 * SZ_C1;
    h0 = (US*)p;                       p += 2 * SZ_H1;
    h1 = (US*)p;
  } else {
    char* p = ws;
    xcP = (US*)p;                      p += SZ_XC;
    dest = (int*)p;                    p += SZ_DEST;
    coefP = (US*)p;                    p += SZ_CP;
    WihP = (US*)p;                     p += SZ_WIHP;
    WhhP = (US*)p;                     p += SZ_WHHP;
    G = (US*)p;                        p += SZ_G1;
    C = (US*)p;                        p += SZ_C1;
    h0 = (US*)p;                       p += SZ_H1;
    h1 = (US*)p;                       p += SZ_H1;
    Outs = (US*)p;
  }
  float* out = (float*)d_out;

  hipMemsetAsync(xcP, 0, SZ_XC, stream);
  scan_k<<<16, SEQL, 0, stream>>>(valid, dest);
  scatter_k<<<(BT * 192) / 256, 256, 0, stream>>>(seq, dest, xcP);
  conv_coef_k<<<288, 256, 0, stream>>>(coef, coefP);
  convW_ih_k<<<dim3(442368 / 256, 1, 2), 256, 0, stream>>>(WihF, WihB, WihP);
  convW_hh_k<<<dim3(221184 / 256, 1, 2), 256, 0, stream>>>(WhhF, WhhB, WhhP);

  if (ndir == 2) {
    gate_gemm_k<<<dim3(64, 12, 6), 256, 0, stream>>>(xcP, WihP, bihF, bihB, bhhF, bhhB,
                                                     G, 0, GE);
    step0_k<<<dim3(BT, 1, 6), HID, 0, stream>>>(G, C, h1, 0, GE, CE, HE);
    for (int s = 1; s < 7; ++s) {
      int nact = (s < 3) ? 3 : ((s < 5) ? 2 : 1);
      int wi0 = 3 - nact;
      US* hcur = (s & 1) ? h1 : h0;
      US* hnxt = (s & 1) ? h0 : h1;
      step_k<<<dim3(64, 12, nact * 2), 256, 0, stream>>>(WhhP, G, C, hcur, hnxt, Outs,
                                                         s, wi0, nact, 0, GE, CE, HE);
    }
  } else {
    for (int dir = 0; dir < 2; ++dir) {
      gate_gemm_k<<<dim3(64, 12, 3), 256, 0, stream>>>(xcP, WihP, bihF, bihB, bhhF, bhhB,
                                                       G, dir, 0);
      step0_k<<<dim3(BT, 1, 3), HID, 0, stream>>>(G, C, h1, dir, 0, 0, 0);
      for (int s = 1; s < 7; ++s) {
        int nact = (s < 3) ? 3 : ((s < 5) ? 2 : 1);
        int wi0 = 3 - nact;
        US* hcur = (s & 1) ? h1 : h0;
        US* hnxt = (s & 1) ? h0 : h1;
        step_k<<<dim3(64, 12, nact), 256, 0, stream>>>(WhhP, G, C, hcur, hnxt, Outs,
                                                       s, wi0, nact, dir, 0, 0, 0);
      }
    }
  }
  attn_kan_k<<<BT / 4, 256, 0, stream>>>(Outs, coefP, kbias, out);
}